// Round 1
// baseline (302.053 us; speedup 1.0000x reference)
//
#include <hip/hip_runtime.h>

typedef float f32x4 __attribute__((ext_vector_type(4)));
typedef short bf16x8 __attribute__((ext_vector_type(8)));
typedef unsigned short u16;
typedef unsigned int u32;

#define MFMA(a, b, c) __builtin_amdgcn_mfma_f32_16x16x32_bf16((a), (b), (c), 0, 0, 0)

static __device__ __forceinline__ u16 f2bf(float f) {
    union { float f; u32 u; } v; v.f = f;
    u32 r = v.u + 0x7FFFu + ((v.u >> 16) & 1u);
    return (u16)(r >> 16);
}

// ---------------------------------------------------------------------------
// Kernel 1: GroupNorm (B=2, C=256, G=32, S=4096) -> normT[b][s][c] bf16
// ---------------------------------------------------------------------------
__global__ __launch_bounds__(256) void gn_kernel(
    const float* __restrict__ x, const float* __restrict__ gw,
    const float* __restrict__ gb, u16* __restrict__ normT) {
    int blk = blockIdx.x;
    int b = blk >> 5, g = blk & 31;
    const float* xp = x + (size_t)(b * 256 + g * 8) * 4096;
    int t = threadIdx.x;

    float s = 0.f, ss = 0.f;
    for (int i = t * 4; i < 32768; i += 1024) {
        float4 v = *(const float4*)(xp + i);
        s += v.x + v.y + v.z + v.w;
        ss += v.x * v.x + v.y * v.y + v.z * v.z + v.w * v.w;
    }
    // wave reduce
    for (int off = 1; off < 64; off <<= 1) {
        s += __shfl_xor(s, off);
        ss += __shfl_xor(ss, off);
    }
    __shared__ float red[8];
    int lane = t & 63, w = t >> 6;
    if (lane == 0) { red[w] = s; red[4 + w] = ss; }
    __syncthreads();
    float tot = red[0] + red[1] + red[2] + red[3];
    float tot2 = red[4] + red[5] + red[6] + red[7];
    float mu = tot * (1.f / 32768.f);
    float var = tot2 * (1.f / 32768.f) - mu * mu;
    float rstd = rsqrtf(var + 1e-5f);

    for (int i = t * 4; i < 32768; i += 1024) {
        int ci = i >> 12;
        int sp = i & 4095;
        float4 v = *(const float4*)(xp + i);
        float wgt = gw[g * 8 + ci] * rstd;
        float bia = gb[g * 8 + ci] - mu * wgt;
        u16* dst = normT + (size_t)(b * 4096 + sp) * 256 + g * 8 + ci;
        dst[0]   = f2bf(v.x * wgt + bia);
        dst[256] = f2bf(v.y * wgt + bia);
        dst[512] = f2bf(v.z * wgt + bia);
        dst[768] = f2bf(v.w * wgt + bia);
    }
}

// ---------------------------------------------------------------------------
// Kernel 2: QKV GEMM. D[o][s] = sum_c W[o][c] * normT[s][c], per (batch, proj)
// 128x128 wg tile, 4 waves (2x2) of 64x64. K=256 in 8 steps of 32.
// Q/K stored (b,h,s,d); V stored (b,h,d,s). Q pre-scaled by 1/16.
// ---------------------------------------------------------------------------
__global__ __launch_bounds__(256) void qkv_gemm(
    const u16* __restrict__ normT, const float* __restrict__ wq,
    const float* __restrict__ wk, const float* __restrict__ wv,
    u16* __restrict__ Q, u16* __restrict__ K, u16* __restrict__ V) {
    int b = blockIdx.y & 1;
    int p = blockIdx.y >> 1;
    const float* W = (p == 0) ? wq : ((p == 1) ? wk : wv);
    int m0 = (blockIdx.x & 1) * 128;
    int n0 = (blockIdx.x >> 1) * 128;

    __shared__ u16 a_s[128 * 40];
    __shared__ u16 b_s[128 * 40];

    int t = threadIdx.x;
    int lane = t & 63, wave = t >> 6;
    int wm = wave & 1, wn = wave >> 1;
    int r = lane & 15, q = lane >> 4;

    const u16* Bsrc = normT + (size_t)b * 4096 * 256;

    f32x4 acc[4][4];
#pragma unroll
    for (int i = 0; i < 4; ++i)
#pragma unroll
        for (int j = 0; j < 4; ++j) acc[i][j] = (f32x4){0.f, 0.f, 0.f, 0.f};

    int srow = t >> 1;
    int scp = (t & 1) * 16;

    for (int kk = 0; kk < 256; kk += 32) {
        __syncthreads();
        // stage A (W fp32 -> bf16): rows m0..m0+127, cols kk..kk+31
        {
            const float* src = W + (m0 + srow) * 256 + kk + scp;
            float4 f0 = *(const float4*)(src + 0);
            float4 f1 = *(const float4*)(src + 4);
            float4 f2 = *(const float4*)(src + 8);
            float4 f3 = *(const float4*)(src + 12);
            float e[16] = {f0.x, f0.y, f0.z, f0.w, f1.x, f1.y, f1.z, f1.w,
                           f2.x, f2.y, f2.z, f2.w, f3.x, f3.y, f3.z, f3.w};
            u16* dst = a_s + srow * 40 + scp;
#pragma unroll
            for (int j = 0; j < 8; ++j) {
                u32 lo = f2bf(e[2 * j]), hi = f2bf(e[2 * j + 1]);
                *(u32*)(dst + 2 * j) = lo | (hi << 16);
            }
        }
        // stage B (normT bf16): rows n0..n0+127 (s), cols kk..kk+31 (c)
        {
            const u16* src = Bsrc + (size_t)(n0 + srow) * 256 + kk + scp;
            *(uint4*)(b_s + srow * 40 + scp) = *(const uint4*)(src);
            *(uint4*)(b_s + srow * 40 + scp + 8) = *(const uint4*)(src + 8);
        }
        __syncthreads();

        bf16x8 af[4], bf[4];
#pragma unroll
        for (int mt = 0; mt < 4; ++mt)
            af[mt] = *(const bf16x8*)(a_s + (wm * 64 + mt * 16 + r) * 40 + q * 8);
#pragma unroll
        for (int nt = 0; nt < 4; ++nt)
            bf[nt] = *(const bf16x8*)(b_s + (wn * 64 + nt * 16 + r) * 40 + q * 8);
#pragma unroll
        for (int mt = 0; mt < 4; ++mt)
#pragma unroll
            for (int nt = 0; nt < 4; ++nt)
                acc[mt][nt] = MFMA(af[mt], bf[nt], acc[mt][nt]);
    }

    // epilogue
#pragma unroll
    for (int mt = 0; mt < 4; ++mt) {
#pragma unroll
        for (int nt = 0; nt < 4; ++nt) {
#pragma unroll
            for (int j = 0; j < 4; ++j) {
                int o = m0 + wm * 64 + mt * 16 + q * 4 + j;
                int s = n0 + wn * 64 + nt * 16 + r;
                float val = acc[mt][nt][j];
                if (p == 0) val *= 0.0625f;  // 1/sqrt(256)
                int h = o >> 6, d = o & 63;
                if (p < 2) {
                    u16* dst = (p == 0) ? Q : K;
                    dst[((size_t)((b * 4 + h) * 4096 + s)) * 64 + d] = f2bf(val);
                } else {
                    V[((size_t)((b * 4 + h) * 64 + d)) * 4096 + s] = f2bf(val);
                }
            }
        }
    }
}

// ---------------------------------------------------------------------------
// Kernel 3: flash attention. Block = 512 thr = 8 waves, each wave 16 queries.
// grid (32 qblocks, 8 bh). K-tile 64 keys. Online softmax.
// ---------------------------------------------------------------------------
__global__ __launch_bounds__(512) void attn_kernel(
    const u16* __restrict__ Q, const u16* __restrict__ K,
    const u16* __restrict__ V, u16* __restrict__ attnT) {
    int qb = blockIdx.x;
    int bh = blockIdx.y;
    int b = bh >> 2, h = bh & 3;
    int t = threadIdx.x, lane = t & 63, w = t >> 6;
    int r = lane & 15, qd = lane >> 4;

    const size_t bhoff = (size_t)bh * 4096 * 64;

    __shared__ u16 ks[64 * 72];
    __shared__ u16 vs[64 * 72];
    __shared__ u16 ps[8][16 * 72];

    int q0 = qb * 128 + w * 16;

    bf16x8 qf0, qf1;
    {
        const u16* qsrc = Q + bhoff + (size_t)(q0 + r) * 64 + qd * 8;
        qf0 = *(const bf16x8*)(qsrc);
        qf1 = *(const bf16x8*)(qsrc + 32);
    }

    f32x4 o_acc[4];
#pragma unroll
    for (int i = 0; i < 4; ++i) o_acc[i] = (f32x4){0.f, 0.f, 0.f, 0.f};
    float m_r[4] = {-1e30f, -1e30f, -1e30f, -1e30f};
    float l_r[4] = {0.f, 0.f, 0.f, 0.f};

    const u16* Ksrc = K + bhoff;
    const u16* Vsrc = V + bhoff;
    int srow = t >> 3, spart = (t & 7) * 8;

    for (int kb = 0; kb < 64; ++kb) {
        int k0 = kb * 64;
        *(uint4*)(ks + srow * 72 + spart) =
            *(const uint4*)(Ksrc + (size_t)(k0 + srow) * 64 + spart);
        *(uint4*)(vs + srow * 72 + spart) =
            *(const uint4*)(Vsrc + (size_t)srow * 4096 + k0 + spart);
        __syncthreads();

        // S = Q K^T  (rows q, cols key)
        f32x4 sf[4];
#pragma unroll
        for (int nt = 0; nt < 4; ++nt) {
            bf16x8 k0f = *(const bf16x8*)(ks + (nt * 16 + r) * 72 + qd * 8);
            bf16x8 k1f = *(const bf16x8*)(ks + (nt * 16 + r) * 72 + 32 + qd * 8);
            f32x4 z = (f32x4){0.f, 0.f, 0.f, 0.f};
            z = MFMA(qf0, k0f, z);
            z = MFMA(qf1, k1f, z);
            sf[nt] = z;
        }

        // online softmax
        float rm[4], alpha[4], rs[4];
#pragma unroll
        for (int j = 0; j < 4; ++j) {
            rm[j] = fmaxf(fmaxf(sf[0][j], sf[1][j]), fmaxf(sf[2][j], sf[3][j]));
            for (int off = 1; off < 16; off <<= 1)
                rm[j] = fmaxf(rm[j], __shfl_xor(rm[j], off));
            float mn = fmaxf(m_r[j], rm[j]);
            alpha[j] = __expf(m_r[j] - mn);
            m_r[j] = mn;
            rs[j] = 0.f;
        }
#pragma unroll
        for (int nt = 0; nt < 4; ++nt) {
#pragma unroll
            for (int j = 0; j < 4; ++j) {
                float pv = __expf(sf[nt][j] - m_r[j]);
                rs[j] += pv;
                ps[w][(qd * 4 + j) * 72 + nt * 16 + r] = f2bf(pv);
            }
        }
#pragma unroll
        for (int j = 0; j < 4; ++j) {
            for (int off = 1; off < 16; off <<= 1) rs[j] += __shfl_xor(rs[j], off);
            l_r[j] = l_r[j] * alpha[j] + rs[j];
        }
#pragma unroll
        for (int nt = 0; nt < 4; ++nt)
#pragma unroll
            for (int j = 0; j < 4; ++j) o_acc[nt][j] *= alpha[j];

        // P back from LDS in A-operand layout
        bf16x8 pf0 = *(const bf16x8*)(&ps[w][r * 72 + qd * 8]);
        bf16x8 pf1 = *(const bf16x8*)(&ps[w][r * 72 + 32 + qd * 8]);

#pragma unroll
        for (int nt = 0; nt < 4; ++nt) {
            bf16x8 v0f = *(const bf16x8*)(vs + (nt * 16 + r) * 72 + qd * 8);
            bf16x8 v1f = *(const bf16x8*)(vs + (nt * 16 + r) * 72 + 32 + qd * 8);
            o_acc[nt] = MFMA(pf0, v0f, o_acc[nt]);
            o_acc[nt] = MFMA(pf1, v1f, o_acc[nt]);
        }
        __syncthreads();
    }

    float inv[4];
#pragma unroll
    for (int j = 0; j < 4; ++j) inv[j] = 1.f / l_r[j];
#pragma unroll
    for (int nt = 0; nt < 4; ++nt) {
#pragma unroll
        for (int j = 0; j < 4; ++j) {
            int qq = q0 + qd * 4 + j;
            int d = nt * 16 + r;
            attnT[(size_t)(b * 4096 + qq) * 256 + h * 64 + d] =
                f2bf(o_acc[nt][j] * inv[j]);
        }
    }
}

// ---------------------------------------------------------------------------
// Kernel 4: output GEMM + bias + residual.
// out[b][o][s] = sum_c Wo[o][c] * attnT[b][s][c] + bo[o] + x[b][o][s]
// ---------------------------------------------------------------------------
__global__ __launch_bounds__(256) void out_gemm(
    const u16* __restrict__ attnT, const float* __restrict__ wo,
    const float* __restrict__ bo, const float* __restrict__ x,
    float* __restrict__ out) {
    int b = blockIdx.y;
    int m0 = (blockIdx.x & 1) * 128;
    int n0 = (blockIdx.x >> 1) * 128;

    __shared__ u16 a_s[128 * 40];
    __shared__ u16 b_s[128 * 40];

    int t = threadIdx.x;
    int lane = t & 63, wave = t >> 6;
    int wm = wave & 1, wn = wave >> 1;
    int r = lane & 15, q = lane >> 4;

    const u16* Bsrc = attnT + (size_t)b * 4096 * 256;

    f32x4 acc[4][4];
#pragma unroll
    for (int i = 0; i < 4; ++i)
#pragma unroll
        for (int j = 0; j < 4; ++j) acc[i][j] = (f32x4){0.f, 0.f, 0.f, 0.f};

    int srow = t >> 1;
    int scp = (t & 1) * 16;

    for (int kk = 0; kk < 256; kk += 32) {
        __syncthreads();
        {
            const float* src = wo + (m0 + srow) * 256 + kk + scp;
            float4 f0 = *(const float4*)(src + 0);
            float4 f1 = *(const float4*)(src + 4);
            float4 f2 = *(const float4*)(src + 8);
            float4 f3 = *(const float4*)(src + 12);
            float e[16] = {f0.x, f0.y, f0.z, f0.w, f1.x, f1.y, f1.z, f1.w,
                           f2.x, f2.y, f2.z, f2.w, f3.x, f3.y, f3.z, f3.w};
            u16* dst = a_s + srow * 40 + scp;
#pragma unroll
            for (int j = 0; j < 8; ++j) {
                u32 lo = f2bf(e[2 * j]), hi = f2bf(e[2 * j + 1]);
                *(u32*)(dst + 2 * j) = lo | (hi << 16);
            }
        }
        {
            const u16* src = Bsrc + (size_t)(n0 + srow) * 256 + kk + scp;
            *(uint4*)(b_s + srow * 40 + scp) = *(const uint4*)(src);
            *(uint4*)(b_s + srow * 40 + scp + 8) = *(const uint4*)(src + 8);
        }
        __syncthreads();

        bf16x8 af[4], bf[4];
#pragma unroll
        for (int mt = 0; mt < 4; ++mt)
            af[mt] = *(const bf16x8*)(a_s + (wm * 64 + mt * 16 + r) * 40 + q * 8);
#pragma unroll
        for (int nt = 0; nt < 4; ++nt)
            bf[nt] = *(const bf16x8*)(b_s + (wn * 64 + nt * 16 + r) * 40 + q * 8);
#pragma unroll
        for (int mt = 0; mt < 4; ++mt)
#pragma unroll
            for (int nt = 0; nt < 4; ++nt)
                acc[mt][nt] = MFMA(af[mt], bf[nt], acc[mt][nt]);
    }

#pragma unroll
    for (int mt = 0; mt < 4; ++mt) {
#pragma unroll
        for (int nt = 0; nt < 4; ++nt) {
#pragma unroll
            for (int j = 0; j < 4; ++j) {
                int o = m0 + wm * 64 + mt * 16 + q * 4 + j;
                int s = n0 + wn * 64 + nt * 16 + r;
                size_t idx = (size_t)(b * 256 + o) * 4096 + s;
                out[idx] = acc[mt][nt][j] + bo[o] + x[idx];
            }
        }
    }
}

// ---------------------------------------------------------------------------
extern "C" void kernel_launch(void* const* d_in, const int* in_sizes, int n_in,
                              void* d_out, int out_size, void* d_ws, size_t ws_size,
                              hipStream_t stream) {
    const float* x = (const float*)d_in[0];
    const float* gn_w = (const float*)d_in[1];
    const float* gn_b = (const float*)d_in[2];
    const float* wq = (const float*)d_in[3];
    const float* wk = (const float*)d_in[4];
    const float* wv = (const float*)d_in[5];
    const float* wo = (const float*)d_in[6];
    const float* bo = (const float*)d_in[7];
    float* out = (float*)d_out;

    char* ws = (char*)d_ws;
    u16* normT = (u16*)(ws);                       // 4 MB: [b][s][c] bf16
    u16* Q     = (u16*)(ws + (4u << 20));          // 4 MB: [b][h][s][d] (pre-scaled)
    u16* Kp    = (u16*)(ws + (8u << 20));          // 4 MB: [b][h][s][d]
    u16* Vp    = (u16*)(ws + (12u << 20));         // 4 MB: [b][h][d][s]
    u16* attnT = (u16*)(ws + (16u << 20));         // 4 MB: [b][s][c]

    gn_kernel<<<64, 256, 0, stream>>>(x, gn_w, gn_b, normT);
    qkv_gemm<<<dim3(64, 6), 256, 0, stream>>>(normT, wq, wk, wv, Q, Kp, Vp);
    attn_kernel<<<dim3(32, 8), 512, 0, stream>>>(Q, Kp, Vp, attnT);
    out_gemm<<<dim3(64, 2), 256, 0, stream>>>(attnT, wo, bo, x, out);
}

// Round 2
// 189.013 us; speedup vs baseline: 1.5981x; 1.5981x over previous
//
#include <hip/hip_runtime.h>

typedef float f32x4 __attribute__((ext_vector_type(4)));
typedef short bf16x8 __attribute__((ext_vector_type(8)));
typedef unsigned short u16;
typedef unsigned int u32;

#define MFMA(a, b, c) __builtin_amdgcn_mfma_f32_16x16x32_bf16((a), (b), (c), 0, 0, 0)

static __device__ __forceinline__ u16 f2bf(float f) {
    union { float f; u32 u; } v; v.f = f;
    u32 r = v.u + 0x7FFFu + ((v.u >> 16) & 1u);
    return (u16)(r >> 16);
}

// ---------------------------------------------------------------------------
// Kernel 0: convert wq/wk/wv fp32 -> bf16 (wq pre-scaled by 1/16).
// Wbf layout: [p][o][c], p=0(q),1(k),2(v); each 256x256.
// ---------------------------------------------------------------------------
__global__ __launch_bounds__(256) void wcvt_kernel(
    const float* __restrict__ wq, const float* __restrict__ wk,
    const float* __restrict__ wv, u16* __restrict__ Wbf) {
    int base = (blockIdx.x * 256 + threadIdx.x) * 4;   // 192 blocks * 1024 = 196608
    int p = base >> 16;
    int off = base & 65535;
    const float* W = (p == 0) ? wq : ((p == 1) ? wk : wv);
    float sc = (p == 0) ? 0.0625f : 1.0f;
    float4 v = *(const float4*)(W + off);
    u32 lo = f2bf(v.x * sc) | ((u32)f2bf(v.y * sc) << 16);
    u32 hi = f2bf(v.z * sc) | ((u32)f2bf(v.w * sc) << 16);
    uint2 pk = {lo, hi};
    *(uint2*)(Wbf + base) = pk;
}

// ---------------------------------------------------------------------------
// Kernel 1: GroupNorm stats. grid 64 = (b,g). stats[b*32+g] = {mu, rstd}
// ---------------------------------------------------------------------------
__global__ __launch_bounds__(256) void gn_stats(
    const float* __restrict__ x, float2* __restrict__ stats) {
    int blk = blockIdx.x;
    int b = blk >> 5, g = blk & 31;
    const float* xp = x + (size_t)(b * 256 + g * 8) * 4096;
    int t = threadIdx.x;

    float s = 0.f, ss = 0.f;
    for (int i = t * 4; i < 32768; i += 1024) {
        float4 v = *(const float4*)(xp + i);
        s += v.x + v.y + v.z + v.w;
        ss += v.x * v.x + v.y * v.y + v.z * v.z + v.w * v.w;
    }
    for (int off = 1; off < 64; off <<= 1) {
        s += __shfl_xor(s, off);
        ss += __shfl_xor(ss, off);
    }
    __shared__ float red[8];
    int lane = t & 63, w = t >> 6;
    if (lane == 0) { red[w] = s; red[4 + w] = ss; }
    __syncthreads();
    if (t == 0) {
        float tot = red[0] + red[1] + red[2] + red[3];
        float tot2 = red[4] + red[5] + red[6] + red[7];
        float mu = tot * (1.f / 32768.f);
        float var = tot2 * (1.f / 32768.f) - mu * mu;
        stats[blk] = make_float2(mu, rsqrtf(var + 1e-5f));
    }
}

// ---------------------------------------------------------------------------
// Kernel 2: GroupNorm apply + transpose -> normT[b][s][c] bf16, coalesced.
// grid (128 s-chunks, 2 b), 256 thr. LDS tile [32 s][264 c-stride].
// ---------------------------------------------------------------------------
__global__ __launch_bounds__(256) void gn_apply(
    const float* __restrict__ x, const float* __restrict__ gw,
    const float* __restrict__ gb, const float2* __restrict__ stats,
    u16* __restrict__ normT) {
    int s0 = blockIdx.x * 32;
    int b = blockIdx.y;
    int t = threadIdx.x;
    __shared__ u16 tile[32 * 264];

    int sj = (t & 7) * 4;
#pragma unroll
    for (int i = 0; i < 8; ++i) {
        int c = (t >> 3) + 32 * i;
        float2 st = stats[b * 32 + (c >> 3)];
        float wgt = gw[c] * st.y;
        float bia = gb[c] - st.x * wgt;
        float4 v = *(const float4*)(x + (size_t)(b * 256 + c) * 4096 + s0 + sj);
        tile[(sj + 0) * 264 + c] = f2bf(v.x * wgt + bia);
        tile[(sj + 1) * 264 + c] = f2bf(v.y * wgt + bia);
        tile[(sj + 2) * 264 + c] = f2bf(v.z * wgt + bia);
        tile[(sj + 3) * 264 + c] = f2bf(v.w * wgt + bia);
    }
    __syncthreads();
#pragma unroll
    for (int k = 0; k < 4; ++k) {
        int idx = t + 256 * k;
        int row = idx >> 5, ch = idx & 31;
        *(uint4*)(normT + ((size_t)(b * 4096 + s0 + row)) * 256 + ch * 8) =
            *(const uint4*)(tile + row * 264 + ch * 8);
    }
}

// ---------------------------------------------------------------------------
// Kernel 3: QKV GEMM (bf16 W). D[o][s] = sum_c W[o][c]*normT[s][c].
// Q/K stored (b,h,s,d) with packed 8B stores; V stored (b,h,d,s).
// ---------------------------------------------------------------------------
__global__ __launch_bounds__(256) void qkv_gemm(
    const u16* __restrict__ normT, const u16* __restrict__ Wbf,
    u16* __restrict__ Q, u16* __restrict__ K, u16* __restrict__ V) {
    int b = blockIdx.y & 1;
    int p = blockIdx.y >> 1;
    const u16* W = Wbf + p * 65536;
    int m0 = (blockIdx.x & 1) * 128;
    int n0 = (blockIdx.x >> 1) * 128;

    __shared__ u16 a_s[128 * 40];
    __shared__ u16 b_s[128 * 40];

    int t = threadIdx.x;
    int lane = t & 63, wave = t >> 6;
    int wm = wave & 1, wn = wave >> 1;
    int r = lane & 15, q = lane >> 4;

    const u16* Bsrc = normT + (size_t)b * 4096 * 256;

    f32x4 acc[4][4];
#pragma unroll
    for (int i = 0; i < 4; ++i)
#pragma unroll
        for (int j = 0; j < 4; ++j) acc[i][j] = (f32x4){0.f, 0.f, 0.f, 0.f};

    int srow = t >> 1;
    int scp = (t & 1) * 16;

    for (int kk = 0; kk < 256; kk += 32) {
        __syncthreads();
        {
            const u16* src = W + (m0 + srow) * 256 + kk + scp;
            *(uint4*)(a_s + srow * 40 + scp) = *(const uint4*)(src);
            *(uint4*)(a_s + srow * 40 + scp + 8) = *(const uint4*)(src + 8);
        }
        {
            const u16* src = Bsrc + (size_t)(n0 + srow) * 256 + kk + scp;
            *(uint4*)(b_s + srow * 40 + scp) = *(const uint4*)(src);
            *(uint4*)(b_s + srow * 40 + scp + 8) = *(const uint4*)(src + 8);
        }
        __syncthreads();

        bf16x8 af[4], bf[4];
#pragma unroll
        for (int mt = 0; mt < 4; ++mt)
            af[mt] = *(const bf16x8*)(a_s + (wm * 64 + mt * 16 + r) * 40 + q * 8);
#pragma unroll
        for (int nt = 0; nt < 4; ++nt)
            bf[nt] = *(const bf16x8*)(b_s + (wn * 64 + nt * 16 + r) * 40 + q * 8);
#pragma unroll
        for (int mt = 0; mt < 4; ++mt)
#pragma unroll
            for (int nt = 0; nt < 4; ++nt)
                acc[mt][nt] = MFMA(af[mt], bf[nt], acc[mt][nt]);
    }

#pragma unroll
    for (int mt = 0; mt < 4; ++mt) {
#pragma unroll
        for (int nt = 0; nt < 4; ++nt) {
            int o0 = m0 + wm * 64 + mt * 16 + q * 4;   // 4 consecutive o
            int s = n0 + wn * 64 + nt * 16 + r;
            int h = o0 >> 6, d0 = o0 & 63;
            if (p < 2) {
                u16* dst = (p == 0) ? Q : K;
                ushort4 pk;
                pk.x = f2bf(acc[mt][nt][0]);
                pk.y = f2bf(acc[mt][nt][1]);
                pk.z = f2bf(acc[mt][nt][2]);
                pk.w = f2bf(acc[mt][nt][3]);
                *(ushort4*)(dst + ((size_t)((b * 4 + h) * 4096 + s)) * 64 + d0) = pk;
            } else {
#pragma unroll
                for (int j = 0; j < 4; ++j) {
                    V[((size_t)((b * 4 + h) * 64 + d0 + j)) * 4096 + s] =
                        f2bf(acc[mt][nt][j]);
                }
            }
        }
    }
}

// ---------------------------------------------------------------------------
// Kernel 4: flash attention v2. 256 thr = 4 waves x 16 q; K-tile 128 keys.
// S^T via A=K, B=Q (col=query). grid (64 qblocks, 8 bh).
// ---------------------------------------------------------------------------
__global__ __launch_bounds__(256, 2) void attn_kernel(
    const u16* __restrict__ Q, const u16* __restrict__ K,
    const u16* __restrict__ V, u16* __restrict__ attnT) {
    int qb = blockIdx.x;
    int bh = blockIdx.y;
    int b = bh >> 2, h = bh & 3;
    int t = threadIdx.x, lane = t & 63, w = t >> 6;
    int r = lane & 15, qd = lane >> 4;

    const size_t bhoff = (size_t)bh * 4096 * 64;

    __shared__ u16 ks[128 * 72];       // [key][d], stride 72
    __shared__ u16 vs[64 * 136];       // [d][key], stride 136
    __shared__ u16 ps[4][16 * 136];    // per-wave [q][key], stride 136

    int q0 = qb * 64 + w * 16;

    bf16x8 qf0, qf1;
    {
        const u16* qsrc = Q + bhoff + (size_t)(q0 + r) * 64 + qd * 8;
        qf0 = *(const bf16x8*)(qsrc);
        qf1 = *(const bf16x8*)(qsrc + 32);
    }

    f32x4 o_acc[4];
#pragma unroll
    for (int i = 0; i < 4; ++i) o_acc[i] = (f32x4){0.f, 0.f, 0.f, 0.f};
    float m_r = -1e30f, l_r = 0.f;

    const u16* Ksrc = K + bhoff;
    const u16* Vsrc = V + bhoff;

    for (int kb = 0; kb < 32; ++kb) {
        int k0 = kb * 128;
        // stage K: 128 rows x 8 chunks; V: 64 rows x 16 chunks
#pragma unroll
        for (int i = 0; i < 4; ++i) {
            int idx = t + 256 * i;
            int krow = idx >> 3, kch = idx & 7;
            *(uint4*)(ks + krow * 72 + kch * 8) =
                *(const uint4*)(Ksrc + (size_t)(k0 + krow) * 64 + kch * 8);
            int vrow = idx >> 4, vch = idx & 15;
            *(uint4*)(vs + vrow * 136 + vch * 8) =
                *(const uint4*)(Vsrc + (size_t)vrow * 4096 + k0 + vch * 8);
        }
        __syncthreads();

        // S^T tiles: D[key][q], col=lane&15=q, row=key=qd*4+j (within kt*16)
        f32x4 sf[8];
#pragma unroll
        for (int kt = 0; kt < 8; ++kt) {
            bf16x8 a0 = *(const bf16x8*)(ks + (kt * 16 + r) * 72 + qd * 8);
            bf16x8 a1 = *(const bf16x8*)(ks + (kt * 16 + r) * 72 + 32 + qd * 8);
            f32x4 z = (f32x4){0.f, 0.f, 0.f, 0.f};
            z = MFMA(a0, qf0, z);
            z = MFMA(a1, qf1, z);
            sf[kt] = z;
        }

        // online softmax: one row (query) per lane&15
        float mx = sf[0][0];
#pragma unroll
        for (int kt = 0; kt < 8; ++kt)
#pragma unroll
            for (int j = 0; j < 4; ++j) mx = fmaxf(mx, sf[kt][j]);
        mx = fmaxf(mx, __shfl_xor(mx, 16));
        mx = fmaxf(mx, __shfl_xor(mx, 32));
        float mnew = fmaxf(m_r, mx);
        float alpha = __expf(m_r - mnew);
        m_r = mnew;

        float rs = 0.f;
#pragma unroll
        for (int kt = 0; kt < 8; ++kt) {
            float p0 = __expf(sf[kt][0] - mnew);
            float p1 = __expf(sf[kt][1] - mnew);
            float p2 = __expf(sf[kt][2] - mnew);
            float p3 = __expf(sf[kt][3] - mnew);
            rs += (p0 + p1) + (p2 + p3);
            ushort4 pk;
            pk.x = f2bf(p0); pk.y = f2bf(p1); pk.z = f2bf(p2); pk.w = f2bf(p3);
            *(ushort4*)(&ps[w][r * 136 + kt * 16 + qd * 4]) = pk;
        }
        rs += __shfl_xor(rs, 16);
        rs += __shfl_xor(rs, 32);
        l_r = l_r * alpha + rs;

#pragma unroll
        for (int dt = 0; dt < 4; ++dt)
#pragma unroll
            for (int j = 0; j < 4; ++j) o_acc[dt][j] *= alpha;

        // O^T += V^T * P^T : A=vs[d][key], B=ps[q][key]
#pragma unroll
        for (int kc = 0; kc < 4; ++kc) {
            bf16x8 pf = *(const bf16x8*)(&ps[w][r * 136 + kc * 32 + qd * 8]);
#pragma unroll
            for (int dt = 0; dt < 4; ++dt) {
                bf16x8 vf = *(const bf16x8*)(vs + (dt * 16 + r) * 136 + kc * 32 + qd * 8);
                o_acc[dt] = MFMA(vf, pf, o_acc[dt]);
            }
        }
        __syncthreads();
    }

    float inv = 1.f / l_r;
    size_t orow = ((size_t)(b * 4096 + q0 + r)) * 256 + h * 64;
#pragma unroll
    for (int dt = 0; dt < 4; ++dt) {
        ushort4 pk;
        pk.x = f2bf(o_acc[dt][0] * inv);
        pk.y = f2bf(o_acc[dt][1] * inv);
        pk.z = f2bf(o_acc[dt][2] * inv);
        pk.w = f2bf(o_acc[dt][3] * inv);
        *(ushort4*)(attnT + orow + dt * 16 + qd * 4) = pk;
    }
}

// ---------------------------------------------------------------------------
// Kernel 5: output GEMM + bias + residual.
// ---------------------------------------------------------------------------
__global__ __launch_bounds__(256) void out_gemm(
    const u16* __restrict__ attnT, const float* __restrict__ wo,
    const float* __restrict__ bo, const float* __restrict__ x,
    float* __restrict__ out) {
    int b = blockIdx.y;
    int m0 = (blockIdx.x & 1) * 128;
    int n0 = (blockIdx.x >> 1) * 128;

    __shared__ u16 a_s[128 * 40];
    __shared__ u16 b_s[128 * 40];

    int t = threadIdx.x;
    int lane = t & 63, wave = t >> 6;
    int wm = wave & 1, wn = wave >> 1;
    int r = lane & 15, q = lane >> 4;

    const u16* Bsrc = attnT + (size_t)b * 4096 * 256;

    f32x4 acc[4][4];
#pragma unroll
    for (int i = 0; i < 4; ++i)
#pragma unroll
        for (int j = 0; j < 4; ++j) acc[i][j] = (f32x4){0.f, 0.f, 0.f, 0.f};

    int srow = t >> 1;
    int scp = (t & 1) * 16;

    for (int kk = 0; kk < 256; kk += 32) {
        __syncthreads();
        {
            const float* src = wo + (m0 + srow) * 256 + kk + scp;
            float4 f0 = *(const float4*)(src + 0);
            float4 f1 = *(const float4*)(src + 4);
            float4 f2 = *(const float4*)(src + 8);
            float4 f3 = *(const float4*)(src + 12);
            float e[16] = {f0.x, f0.y, f0.z, f0.w, f1.x, f1.y, f1.z, f1.w,
                           f2.x, f2.y, f2.z, f2.w, f3.x, f3.y, f3.z, f3.w};
            u16* dst = a_s + srow * 40 + scp;
#pragma unroll
            for (int j = 0; j < 8; ++j) {
                u32 lo = f2bf(e[2 * j]), hi = f2bf(e[2 * j + 1]);
                *(u32*)(dst + 2 * j) = lo | (hi << 16);
            }
        }
        {
            const u16* src = Bsrc + (size_t)(n0 + srow) * 256 + kk + scp;
            *(uint4*)(b_s + srow * 40 + scp) = *(const uint4*)(src);
            *(uint4*)(b_s + srow * 40 + scp + 8) = *(const uint4*)(src + 8);
        }
        __syncthreads();

        bf16x8 af[4], bf[4];
#pragma unroll
        for (int mt = 0; mt < 4; ++mt)
            af[mt] = *(const bf16x8*)(a_s + (wm * 64 + mt * 16 + r) * 40 + q * 8);
#pragma unroll
        for (int nt = 0; nt < 4; ++nt)
            bf[nt] = *(const bf16x8*)(b_s + (wn * 64 + nt * 16 + r) * 40 + q * 8);
#pragma unroll
        for (int mt = 0; mt < 4; ++mt)
#pragma unroll
            for (int nt = 0; nt < 4; ++nt)
                acc[mt][nt] = MFMA(af[mt], bf[nt], acc[mt][nt]);
    }

#pragma unroll
    for (int mt = 0; mt < 4; ++mt) {
#pragma unroll
        for (int nt = 0; nt < 4; ++nt) {
#pragma unroll
            for (int j = 0; j < 4; ++j) {
                int o = m0 + wm * 64 + mt * 16 + q * 4 + j;
                int s = n0 + wn * 64 + nt * 16 + r;
                size_t idx = (size_t)(b * 256 + o) * 4096 + s;
                out[idx] = acc[mt][nt][j] + bo[o] + x[idx];
            }
        }
    }
}

// ---------------------------------------------------------------------------
extern "C" void kernel_launch(void* const* d_in, const int* in_sizes, int n_in,
                              void* d_out, int out_size, void* d_ws, size_t ws_size,
                              hipStream_t stream) {
    const float* x = (const float*)d_in[0];
    const float* gn_w = (const float*)d_in[1];
    const float* gn_b = (const float*)d_in[2];
    const float* wq = (const float*)d_in[3];
    const float* wk = (const float*)d_in[4];
    const float* wv = (const float*)d_in[5];
    const float* wo = (const float*)d_in[6];
    const float* bo = (const float*)d_in[7];
    float* out = (float*)d_out;

    char* ws = (char*)d_ws;
    u16* normT = (u16*)(ws);                        // [0,4M): [b][s][c] bf16
    u16* Q     = (u16*)(ws + (4u << 20));           // [4,8M): [b][h][s][d] (pre-scaled)
    u16* Kp    = (u16*)(ws + (8u << 20));           // [8,12M): [b][h][s][d]
    u16* Vp    = (u16*)(ws + (12u << 20));          // [12,16M): [b][h][d][s]
    u16* attnT = (u16*)(ws + (16u << 20));          // [16,20M): [b][s][c]
    // transient region inside [16,20M): Wbf (384 KB) + stats (512 B),
    // consumed by qkv/gn_apply BEFORE attn_kernel overwrites with attnT.
    u16* Wbf     = (u16*)(ws + (16u << 20));
    float2* stats = (float2*)(ws + (16u << 20) + 393216);

    wcvt_kernel<<<192, 256, 0, stream>>>(wq, wk, wv, Wbf);
    gn_stats<<<64, 256, 0, stream>>>(x, stats);
    gn_apply<<<dim3(128, 2), 256, 0, stream>>>(x, gn_w, gn_b, stats, normT);
    qkv_gemm<<<dim3(64, 6), 256, 0, stream>>>(normT, Wbf, Q, Kp, Vp);
    attn_kernel<<<dim3(64, 8), 256, 0, stream>>>(Q, Kp, Vp, attnT);
    out_gemm<<<dim3(64, 2), 256, 0, stream>>>(attnT, wo, bo, x, out);
}